// Round 4
// baseline (195.505 us; speedup 1.0000x reference)
//
#include <hip/hip_runtime.h>
#include <hip/hip_bf16.h>

// Problem constants (B=64, T=2048, D=512, U=512)
#define BB 64
#define TT 2048
#define DD 512
#define UU 512
#define MM (BB * TT)                 // 131072 rows
#define CTX_ELEMS (BB * DD)          // context region of d_out
#define ATTN_OFF  CTX_ELEMS          // attention region offset in d_out

typedef __bf16 bf16x8 __attribute__((ext_vector_type(8)));
typedef float  f32x4  __attribute__((ext_vector_type(4)));
typedef unsigned short u16x8 __attribute__((ext_vector_type(8)));
typedef unsigned int u32;

#define GLOBAL_AS __attribute__((address_space(1)))
#define LDS_AS    __attribute__((address_space(3)))

__device__ __forceinline__ unsigned short f2bf(float f) {
    union { float f; unsigned u; } x; x.f = f;
    unsigned r = x.u + 0x7fffu + ((x.u >> 16) & 1u);   // RNE
    return (unsigned short)(r >> 16);
}

__device__ __forceinline__ float tanh_fast(float x) {
    x = fminf(fmaxf(x, -10.f), 10.f);                  // avoid inf*0
    float e = __builtin_amdgcn_exp2f(x * 2.885390082f); // e^(2x)
    return (e - 1.0f) * __builtin_amdgcn_rcpf(e + 1.0f);
}

// ---------------------------------------------------------------------------
// Kernel 1: W1 [D][U] f32 -> W1T bf16, tiled layout:
//   tile ti = (nt*16 + kt), nt = u>>7, kt = d>>5  (8 KB per tile)
//   within tile: [kc(4)][n(128)][e(8)] : kc = (d&31)>>3, n = u&127, e = d&7
// ---------------------------------------------------------------------------
__global__ void k_w1t(const float* __restrict__ W1, unsigned short* __restrict__ W1T) {
    int gid = blockIdx.x * 256 + threadIdx.x;   // 32768 threads
    int u  = gid & 511;
    int dc = gid >> 9;                          // d-chunk of 8, 0..63
    int d0 = dc * 8;
    u16x8 pk;
    #pragma unroll
    for (int e = 0; e < 8; ++e)
        pk[e] = f2bf(W1[(size_t)(d0 + e) * UU + u]);
    int nt = u >> 7, n = u & 127;
    int kt = dc >> 2, kc = dc & 3;
    size_t off = ((size_t)(nt * 16 + kt) * 8192 + kc * 2048 + n * 16) / 2;
    *(u16x8*)(W1T + off) = pk;
}

// ---------------------------------------------------------------------------
// Kernel 2: phc[b][u] = b1[u] + b2[u] + hidden[b,:] @ W2[:,u]
// ---------------------------------------------------------------------------
__global__ void k_phc(const float* __restrict__ hidden, const float* __restrict__ W2,
                      const float* __restrict__ b1, const float* __restrict__ b2,
                      float* __restrict__ phc) {
    const int b = blockIdx.x;
    const int u = threadIdx.x;         // 512 threads
    const float* h = hidden + (size_t)b * DD;
    float acc = b1[u] + b2[u];
    #pragma unroll 8
    for (int d = 0; d < DD; ++d)
        acc += h[d] * W2[(size_t)d * UU + u];
    phc[(size_t)b * UU + u] = acc;
}

// ---------------------------------------------------------------------------
// Kernel 3: partial-score GEMM, counted-vmcnt pipeline (T3-min + T4).
// Tile BM=128 x BN=128 x BK=32, 256 threads = 4 waves (2x2 of 64x64).
// Triple-buffered LDS (A and B), raw s_barrier (ONE per K-step), prefetch
// depth 2, steady-state wait is vmcnt(6) -- never 0 -- so loads stay in
// flight across barriers (the m97-structure drain was Round-3's stall).
// Grid 4096 = (gx 0..1023) x (gy 0..3), XCD-swizzled for A-tile L2 reuse.
// ---------------------------------------------------------------------------
__launch_bounds__(256, 3)
__global__ void k_score(const float* __restrict__ feat,
                        const unsigned short* __restrict__ W1T,
                        const float* __restrict__ phc,
                        const float* __restrict__ V,
                        float* __restrict__ part) {
    __shared__ __align__(16) unsigned short sA[3 * 4096];  // 3 x 8 KB
    __shared__ __align__(16) unsigned short sB[3 * 4096];  // 3 x 8 KB
    __shared__ float sRed[4][64];

    const int tid  = threadIdx.x;
    const int lane = tid & 63;
    const int w    = tid >> 6;                // wave 0..3
    const int wr   = w >> 1, wc = w & 1;

    // XCD-aware decomposition
    const int rb  = blockIdx.x;
    const int xcd = rb & 7;
    const int uu  = rb >> 3;
    const int gy  = uu & 3;
    const int gx  = xcd * 128 + (uu >> 2);
    const int m0  = gx * 128;
    const int b   = m0 >> 11;

    const char* bslab0 = (const char*)W1T + (size_t)gy * 16 * 8192;
    const char* fbase0 = (const char*)feat + (size_t)m0 * 2048;

    const int r = tid >> 1;                   // staging row 0..127
    const int h = tid & 1;                    // k-half (16 floats)
    const char* fA = fbase0 + (size_t)r * 2048 + h * 64;

    f32x4 pA0, pA1, pA2, pA3, pB0, pB1, pB2, pB3;

    f32x4 acc[4][4];
    #pragma unroll
    for (int i = 0; i < 4; ++i)
        #pragma unroll
        for (int j = 0; j < 4; ++j)
            acc[i][j] = (f32x4){0.f, 0.f, 0.f, 0.f};

#define VM6()   asm volatile("s_waitcnt vmcnt(6)" ::: "memory")
#define VM0()   asm volatile("s_waitcnt vmcnt(0)" ::: "memory")
#define LGKM0() asm volatile("s_waitcnt lgkmcnt(0)" ::: "memory")
#define BAR()   __builtin_amdgcn_s_barrier()

#define STAGE_B(bufi_, kt_) do {                                                   \
    const char* bs_ = bslab0 + (kt_) * 8192;                                       \
    _Pragma("unroll")                                                              \
    for (int p_ = 0; p_ < 2; ++p_) {                                               \
        const char* src_ = bs_ + (size_t)(p_ * 256 + tid) * 16;                    \
        char* dst_ = (char*)sB + (bufi_) * 8192 + (size_t)(p_ * 256 + (tid & ~63)) * 16; \
        __builtin_amdgcn_global_load_lds((const GLOBAL_AS u32*)src_,               \
                                         (LDS_AS u32*)dst_, 16, 0, 0);             \
    } } while (0)

#define LOAD_A(P, kt_) do {                                                        \
    const char* s_ = fA + (kt_) * 128;                                             \
    P##0 = *(const f32x4*)(s_);                                                    \
    P##1 = *(const f32x4*)(s_ + 16);                                               \
    P##2 = *(const f32x4*)(s_ + 32);                                               \
    P##3 = *(const f32x4*)(s_ + 48); } while (0)

#define WRITE_A(bufi_, P) do {                                                     \
    bf16x8 q0_, q1_;                                                               \
    _Pragma("unroll")                                                              \
    for (int j_ = 0; j_ < 4; ++j_) {                                               \
        q0_[j_] = (__bf16)P##0[j_]; q0_[4 + j_] = (__bf16)P##1[j_];                \
        q1_[j_] = (__bf16)P##2[j_]; q1_[4 + j_] = (__bf16)P##3[j_];                \
    }                                                                              \
    *(bf16x8*)((char*)sA + (bufi_) * 8192 + (2 * h) * 2048 + r * 16) = q0_;        \
    *(bf16x8*)((char*)sA + (bufi_) * 8192 + (2 * h + 1) * 2048 + r * 16) = q1_; } while (0)

#define FRAG_READ(c0_) do {                                                        \
    const int kc_ = lane >> 4;                                                     \
    _Pragma("unroll")                                                              \
    for (int ns_ = 0; ns_ < 4; ++ns_)                                              \
        bfr[ns_] = *(const bf16x8*)((const char*)sB + (c0_) * 8192 + kc_ * 2048 +  \
                                    (wc * 64 + ns_ * 16 + (lane & 15)) * 16);      \
    _Pragma("unroll")                                                              \
    for (int ms_ = 0; ms_ < 4; ++ms_)                                              \
        af[ms_] = *(const bf16x8*)((const char*)sA + (c0_) * 8192 + kc_ * 2048 +   \
                                   (wr * 64 + ms_ * 16 + (lane & 15)) * 16); } while (0)

#define MFMA_DO() do {                                                             \
    __builtin_amdgcn_s_setprio(1);                                                 \
    _Pragma("unroll")                                                              \
    for (int ms_ = 0; ms_ < 4; ++ms_)                                              \
        _Pragma("unroll")                                                          \
        for (int ns_ = 0; ns_ < 4; ++ns_)                                          \
            acc[ms_][ns_] = __builtin_amdgcn_mfma_f32_16x16x32_bf16(af[ms_], bfr[ns_], acc[ms_][ns_], 0, 0, 0); \
    __builtin_amdgcn_s_setprio(0); } while (0)

// One K-step. RA holds A(kt+1) f32 (in flight); RB is loaded with A(kt+2).
#define BODY(kt_, RA, RB, PRE, LAST)  do {                                         \
    bf16x8 af[4], bfr[4];                                                          \
    FRAG_READ((kt_) % 3);                                                          \
    if (PRE) { STAGE_B(((kt_) + 2) % 3, (kt_) + 2); LOAD_A(RB, (kt_) + 2); }       \
    MFMA_DO();                                                                     \
    if (LAST) { VM0(); } else { VM6(); }                                           \
    WRITE_A(((kt_) + 1) % 3, RA);                                                  \
    LGKM0();                                                                       \
    BAR(); } while (0)

    // ---- prologue: fill buf0, start buf1 ----
    STAGE_B(0, 0);        // vm += 2
    LOAD_A(pB, 0);        // vm += 4  (A(0))
    STAGE_B(1, 1);        // vm += 2
    LOAD_A(pA, 1);        // vm += 4  (A(1))
    VM6();                // B(0)+A(0) arrived
    WRITE_A(0, pB);
    LGKM0();
    BAR();
    // invariant: buf0 complete; outstanding = B(1):2 + A(1):4 = 6; pA = A(1)

    BODY(0,  pA, pB, 1, 0);  BODY(1,  pB, pA, 1, 0);
    BODY(2,  pA, pB, 1, 0);  BODY(3,  pB, pA, 1, 0);
    BODY(4,  pA, pB, 1, 0);  BODY(5,  pB, pA, 1, 0);
    BODY(6,  pA, pB, 1, 0);  BODY(7,  pB, pA, 1, 0);
    BODY(8,  pA, pB, 1, 0);  BODY(9,  pB, pA, 1, 0);
    BODY(10, pA, pB, 1, 0);  BODY(11, pB, pA, 1, 0);
    BODY(12, pA, pB, 1, 0);  BODY(13, pB, pA, 1, 0);
    BODY(14, pA, pB, 0, 1);             // no prefetch; drain (only 6 left)
    {                                    // kt = 15: compute only
        bf16x8 af[4], bfr[4];
        FRAG_READ(0);
        MFMA_DO();
    }

#undef BODY
#undef MFMA_DO
#undef FRAG_READ
#undef WRITE_A
#undef LOAD_A
#undef STAGE_B
#undef VM6
#undef VM0
#undef LGKM0
#undef BAR

    // --- epilogue: partial score over this block's 128 n-cols ---
    float pc[4], vv[4];
    #pragma unroll
    for (int ns = 0; ns < 4; ++ns) {
        int ug = gy * 128 + wc * 64 + ns * 16 + (lane & 15);
        pc[ns] = phc[(size_t)b * UU + ug];
        vv[ns] = V[ug];
    }
    float pr[4][4];
    #pragma unroll
    for (int ms = 0; ms < 4; ++ms)
        #pragma unroll
        for (int rg = 0; rg < 4; ++rg) {
            float s = 0.f;
            #pragma unroll
            for (int ns = 0; ns < 4; ++ns)
                s += tanh_fast(acc[ms][ns][rg] + pc[ns]) * vv[ns];
            pr[ms][rg] = s;
        }
    #pragma unroll
    for (int off = 1; off < 16; off <<= 1)
        #pragma unroll
        for (int ms = 0; ms < 4; ++ms)
            #pragma unroll
            for (int rg = 0; rg < 4; ++rg)
                pr[ms][rg] += __shfl_xor(pr[ms][rg], off, 64);
    if ((lane & 15) == 0) {
        int rowg = lane >> 4;
        #pragma unroll
        for (int ms = 0; ms < 4; ++ms)
            #pragma unroll
            for (int rg = 0; rg < 4; ++rg)
                sRed[w][ms * 16 + rowg * 4 + rg] = pr[ms][rg];
    }
    __syncthreads();
    if (tid < 128) {
        int wrx = tid >> 6, ml = tid & 63;
        float v = sRed[2 * wrx][ml] + sRed[2 * wrx + 1][ml];
        part[(size_t)gy * MM + m0 + tid] = v;
    }
}

// ---------------------------------------------------------------------------
// Kernel 4: sum 4 partials -> softmax over T -> d_out attn region.
// ---------------------------------------------------------------------------
__global__ void k_softmax(const float* __restrict__ part, float* __restrict__ dout) {
    const int b = blockIdx.x, tid = threadIdx.x;   // 256 threads
    float* sc = dout + ATTN_OFF + (size_t)b * TT;
    float v[8];
    float mx = -3.4e38f;
    #pragma unroll
    for (int i = 0; i < 8; ++i) {
        int t = tid + 256 * i;
        size_t idx = (size_t)b * TT + t;
        v[i] = part[idx] + part[MM + idx] + part[2 * MM + idx] + part[3 * MM + idx];
        mx = fmaxf(mx, v[i]);
    }
    __shared__ float red[256];
    red[tid] = mx; __syncthreads();
    for (int s = 128; s >= 1; s >>= 1) {
        if (tid < s) red[tid] = fmaxf(red[tid], red[tid + s]);
        __syncthreads();
    }
    mx = red[0]; __syncthreads();
    float sum = 0.f;
    #pragma unroll
    for (int i = 0; i < 8; ++i) { v[i] = __expf(v[i] - mx); sum += v[i]; }
    red[tid] = sum; __syncthreads();
    for (int s = 128; s >= 1; s >>= 1) {
        if (tid < s) red[tid] += red[tid + s];
        __syncthreads();
    }
    float inv = 1.0f / red[0];
    #pragma unroll
    for (int i = 0; i < 8; ++i) sc[tid + 256 * i] = v[i] * inv;
}

// ---------------------------------------------------------------------------
// Kernel 5: context[b][d] = sum_t w[b][t] * feat[b][t][d]
// grid (64, 8); 256 threads = 16 d-quads (float4) x 16 t-subgroups.
// ---------------------------------------------------------------------------
__global__ void k_context(const float* __restrict__ feat, float* __restrict__ dout) {
    const int b = blockIdx.x, dc = blockIdx.y;
    const int dq = threadIdx.x & 15;          // float4 lane
    const int ty = threadIdx.x >> 4;          // 0..15
    const int d = dc * 64 + dq * 4;
    const float* wgt = dout + ATTN_OFF + (size_t)b * TT;
    const float* f = feat + (size_t)b * TT * DD + d;
    float4 acc = {0.f, 0.f, 0.f, 0.f};
    #pragma unroll 4
    for (int i = 0; i < TT / 16; ++i) {
        int t = i * 16 + ty;
        float wv = wgt[t];
        float4 fv = *(const float4*)(f + (size_t)t * DD);
        acc.x += wv * fv.x; acc.y += wv * fv.y;
        acc.z += wv * fv.z; acc.w += wv * fv.w;
    }
    __shared__ float4 red[16][16];
    red[ty][dq] = acc; __syncthreads();
    if (ty == 0) {
        float4 s = red[0][dq];
        #pragma unroll
        for (int k = 1; k < 16; ++k) {
            float4 r = red[k][dq];
            s.x += r.x; s.y += r.y; s.z += r.z; s.w += r.w;
        }
        *(float4*)(dout + (size_t)b * DD + d) = s;
    }
}

// ---------------------------------------------------------------------------
extern "C" void kernel_launch(void* const* d_in, const int* in_sizes, int n_in,
                              void* d_out, int out_size, void* d_ws, size_t ws_size,
                              hipStream_t stream) {
    (void)in_sizes; (void)n_in; (void)out_size; (void)ws_size;
    const float* feat   = (const float*)d_in[0];
    const float* hidden = (const float*)d_in[1];
    const float* W1     = (const float*)d_in[2];
    const float* b1     = (const float*)d_in[3];
    const float* W2     = (const float*)d_in[4];
    const float* b2     = (const float*)d_in[5];
    const float* V      = (const float*)d_in[6];
    // d_in[7] = bV : softmax-invariant constant, unused.

    // ws layout: [0,512K) W1T bf16; [512K,640K) phc f32; [640K,640K+2M) partials
    unsigned short* W1T = (unsigned short*)d_ws;
    float* phc  = (float*)((char*)d_ws + 512 * 1024);
    float* part = (float*)((char*)d_ws + 640 * 1024);
    float* out  = (float*)d_out;

    hipLaunchKernelGGL(k_w1t,     dim3(128),    dim3(256), 0, stream, W1, W1T);
    hipLaunchKernelGGL(k_phc,     dim3(64),     dim3(512), 0, stream, hidden, W2, b1, b2, phc);
    hipLaunchKernelGGL(k_score,   dim3(4096),   dim3(256), 0, stream, feat, W1T, phc, V, part);
    hipLaunchKernelGGL(k_softmax, dim3(64),     dim3(256), 0, stream, part, out);
    hipLaunchKernelGGL(k_context, dim3(64, 8),  dim3(256), 0, stream, feat, out);
}